// Round 2
// baseline (421.654 us; speedup 1.0000x reference)
//
#include <hip/hip_runtime.h>
#include <stdint.h>

// Problem constants (B,S,D fixed by the reference)
#define B_  4
#define S_  2048
#define D_  1024
#define DK_ 1024
#define DV_ 1024

typedef __attribute__((ext_vector_type(8))) short  short8;   // 8 bf16 = 4 VGPRs (MFMA A/B frag)
typedef __attribute__((ext_vector_type(4))) float  floatx4;  // MFMA C/D frag

// async global->LDS DMA, 16B per lane, wave-uniform LDS base (lane scatters +lane*16B)
#define ASYNC16(gsrc, ldst)                                                        \
  __builtin_amdgcn_global_load_lds(                                                \
      (const __attribute__((address_space(1))) unsigned int*)(gsrc),               \
      (__attribute__((address_space(3))) unsigned int*)(ldst), 16, 0, 0)

// round-to-nearest-even fp32 -> bf16 (bit trick; inputs are normal floats)
__device__ __forceinline__ unsigned short f2bf(float f) {
  union { float f; uint32_t u; } v; v.f = f;
  uint32_t r = v.u + 0x7fffu + ((v.u >> 16) & 1u);
  return (unsigned short)(r >> 16);
}

// ---------------- fp32 -> bf16 elementwise (n divisible by 1024) ----------------
__global__ __launch_bounds__(256) void cvt_f32_bf16(const float* __restrict__ in,
                                                    unsigned short* __restrict__ out, int n4) {
  int i = blockIdx.x * blockDim.x + threadIdx.x;
  if (i >= n4) return;
  float4 v = ((const float4*)in)[i];
  ushort4 o;
  o.x = f2bf(v.x); o.y = f2bf(v.y); o.z = f2bf(v.z); o.w = f2bf(v.w);
  ((ushort4*)out)[i] = o;
}

// ---------------- transpose fp32 [rows,cols] -> bf16 [cols,rows] ----------------
__global__ __launch_bounds__(256) void transpose_f32_bf16(const float* __restrict__ in,
                                                          unsigned short* __restrict__ out,
                                                          int rows, int cols) {
  __shared__ float tile[32][33];  // +1 pad: no bank conflicts
  int bx = blockIdx.x * 32, by = blockIdx.y * 32;
  int tx = threadIdx.x & 31, ty = threadIdx.x >> 5;  // 256 thr: ty 0..7
  for (int r = ty; r < 32; r += 8)
    tile[r][tx] = in[(long)(by + r) * cols + bx + tx];
  __syncthreads();
  for (int r = ty; r < 32; r += 8)
    out[(long)(bx + r) * rows + by + tx] = f2bf(tile[tx][r]);
}

// ---------------- transpose bf16 [rows,cols] -> bf16 [cols,rows], batched on z ----------------
__global__ __launch_bounds__(256) void transpose_bf16_batched(const unsigned short* __restrict__ in,
                                                              unsigned short* __restrict__ out,
                                                              int rows, int cols) {
  in  += (long)blockIdx.z * rows * cols;
  out += (long)blockIdx.z * rows * cols;
  __shared__ unsigned short tile[32][33];
  int bx = blockIdx.x * 32, by = blockIdx.y * 32;
  int tx = threadIdx.x & 31, ty = threadIdx.x >> 5;
  for (int r = ty; r < 32; r += 8)
    tile[r][tx] = in[(long)(by + r) * cols + bx + tx];
  __syncthreads();
  for (int r = ty; r < 32; r += 8)
    out[(long)(bx + r) * rows + by + tx] = tile[tx][r];
}

// ---------------- output store helpers ----------------
__device__ __forceinline__ void storeC(float* p, float v)          { *p = v; }
__device__ __forceinline__ void storeC(unsigned short* p, float v) { *p = f2bf(v); }

// ---------------- bf16 BT GEMM: C[M,N] = scale * (A[M,K] · B[N,K]^T) + bias ----------------
// 128x128 block tile, 4 waves (2x2 of 64x64), BK=32, v_mfma_f32_16x16x32_bf16.
// Staging via global_load_lds width=16 (m97 structure): each wave DMAs 2 KB of A and
// 2 KB of B per K-iter as 4 async 1KB chunks. LDS chunk c covers rows [c*16, c*16+16)
// of the unpadded row-major [128][32] tile; HW scatters lane l at base + l*16B, i.e.
// row c*16 + l/4, colchunk (l&3)*8 -- global addresses below match exactly.
template <typename OutT>
__global__ __launch_bounds__(256)
void gemm_bt(const unsigned short* __restrict__ A, const unsigned short* __restrict__ Bm,
             OutT* __restrict__ C, const float* __restrict__ bias,
             int M, int N, int K, long sA, long sB, long sC, float scale) {
  __shared__ __align__(16) unsigned short As[128 * 32];
  __shared__ __align__(16) unsigned short Bs[128 * 32];
  const int tid  = threadIdx.x;
  const int lane = tid & 63, wave = tid >> 6;
  const int wm = (wave >> 1) * 64, wn = (wave & 1) * 64;
  const int lm = lane & 15, lq = lane >> 4;
  const long zb = blockIdx.z;
  A  += zb * sA;  Bm += zb * sB;  C += zb * sC;
  const int m0 = blockIdx.y * 128, n0 = blockIdx.x * 128;

  // staging: wave w owns chunks w and w+4 of both A and B tiles
  const int r0 = wave * 16 + (lane >> 2);   // chunk w rows
  const int r1 = r0 + 64;                   // chunk w+4 rows
  const int cc = (lane & 3) * 8;            // 8-elem col chunk
  const unsigned short* Agp0 = A  + (long)(m0 + r0) * K + cc;
  const unsigned short* Agp1 = A  + (long)(m0 + r1) * K + cc;
  const unsigned short* Bgp0 = Bm + (long)(n0 + r0) * K + cc;
  const unsigned short* Bgp1 = Bm + (long)(n0 + r1) * K + cc;
  unsigned short* AsL0 = &As[wave * 512];          // wave-uniform LDS bases
  unsigned short* AsL1 = &As[(wave + 4) * 512];
  unsigned short* BsL0 = &Bs[wave * 512];
  unsigned short* BsL1 = &Bs[(wave + 4) * 512];

  floatx4 acc[4][4] = {};  // zero-init accumulators (AGPRs)

  for (int k0 = 0; k0 < K; k0 += 32) {
    __syncthreads();              // previous compute done reading LDS
    ASYNC16(Agp0 + k0, AsL0);
    ASYNC16(Agp1 + k0, AsL1);
    ASYNC16(Bgp0 + k0, BsL0);
    ASYNC16(Bgp1 + k0, BsL1);
    __syncthreads();              // drains vmcnt -> tiles visible

    short8 af[4], bf[4];
#pragma unroll
    for (int i = 0; i < 4; i++)
      af[i] = *(const short8*)&As[(wm + i * 16 + lm) * 32 + lq * 8];
#pragma unroll
    for (int j = 0; j < 4; j++)
      bf[j] = *(const short8*)&Bs[(wn + j * 16 + lm) * 32 + lq * 8];
#pragma unroll
    for (int i = 0; i < 4; i++)
#pragma unroll
      for (int j = 0; j < 4; j++)
        acc[i][j] = __builtin_amdgcn_mfma_f32_16x16x32_bf16(af[i], bf[j], acc[i][j], 0, 0, 0);
  }

  // epilogue: C/D layout col=lane&15, row=(lane>>4)*4+t
#pragma unroll
  for (int i = 0; i < 4; i++) {
    int row = m0 + wm + i * 16 + lq * 4;
#pragma unroll
    for (int j = 0; j < 4; j++) {
      int col = n0 + wn + j * 16 + lm;
      float bv = bias ? bias[col] : 0.f;
#pragma unroll
      for (int t = 0; t < 4; t++) {
        float val = acc[i][j][t] * scale + bv;
        storeC(C + (long)(row + t) * N + col, val);
      }
    }
  }
}

// ---------------- row softmax: fp32 [rows,2048] -> bf16 probs ----------------
__global__ __launch_bounds__(256) void softmax_rows(const float* __restrict__ Sc,
                                                    unsigned short* __restrict__ P) {
  const long row = blockIdx.x;
  const float* x = Sc + row * 2048;
  unsigned short* p = P + row * 2048;
  const int tid = threadIdx.x;
  float v[8];
  float m = -3.4e38f;
#pragma unroll
  for (int j = 0; j < 8; j++) { v[j] = x[tid + j * 256]; m = fmaxf(m, v[j]); }
#pragma unroll
  for (int off = 32; off > 0; off >>= 1) m = fmaxf(m, __shfl_xor(m, off, 64));
  __shared__ float redm[4], reds[4];
  if ((tid & 63) == 0) redm[tid >> 6] = m;
  __syncthreads();
  m = fmaxf(fmaxf(redm[0], redm[1]), fmaxf(redm[2], redm[3]));
  float s = 0.f;
#pragma unroll
  for (int j = 0; j < 8; j++) { v[j] = __expf(v[j] - m); s += v[j]; }
#pragma unroll
  for (int off = 32; off > 0; off >>= 1) s += __shfl_xor(s, off, 64);
  if ((tid & 63) == 0) reds[tid >> 6] = s;
  __syncthreads();
  s = reds[0] + reds[1] + reds[2] + reds[3];
  float inv = 1.f / s;
#pragma unroll
  for (int j = 0; j < 8; j++) p[tid + j * 256] = f2bf(v[j] * inv);
}

extern "C" void kernel_launch(void* const* d_in, const int* in_sizes, int n_in,
                              void* d_out, int out_size, void* d_ws, size_t ws_size,
                              hipStream_t stream) {
  const float* q_in = (const float*)d_in[0];
  const float* k_in = (const float*)d_in[1];
  const float* v_in = (const float*)d_in[2];
  const float* Wq   = (const float*)d_in[3];
  const float* bq   = (const float*)d_in[4];
  const float* Wk   = (const float*)d_in[5];
  const float* bk   = (const float*)d_in[6];
  const float* Wv   = (const float*)d_in[7];
  const float* bv   = (const float*)d_in[8];
  float* out = (float*)d_out;

  // ---- workspace layout (bytes). scores overlays regions dead by the time it is written. ----
  char* ws = (char*)d_ws;
  const long nX  = (long)B_ * S_ * D_;       // 8388608 elems per tensor
  const long nW  = (long)D_ * DK_;           // 1048576
  unsigned short* qb  = (unsigned short*)(ws);                       // [0, 16MB)
  unsigned short* kb  = qb + nX;                                     // [16, 32MB)
  unsigned short* vb  = kb + nX;                                     // [32, 48MB)
  unsigned short* WqT = vb + nX;                                     // [48, 50MB)
  unsigned short* WkT = WqT + nW;
  unsigned short* WvT = WkT + nW;                                    // ends at 54,525,952
  unsigned short* Vb  = WvT + nW;                                    // V bf16 [B,S,DV], dead after transpose
  unsigned short* Qb  = Vb + nX;
  unsigned short* Kb  = Qb + nX;
  unsigned short* Vt  = Kb + nX;                                     // [B, DV, S]
  float*          scores = (float*)ws;                               // overlay [0, 64MB): qb/kb/vb/WT/Vb dead
  unsigned short* attn   = Vt + nX;                                  // after Vt

  dim3 blk(256);

  // 1) inputs -> bf16
  {
    int n4 = (int)(nX / 4);
    dim3 g(n4 / 256);
    cvt_f32_bf16<<<g, blk, 0, stream>>>(q_in, qb, n4);
    cvt_f32_bf16<<<g, blk, 0, stream>>>(k_in, kb, n4);
    cvt_f32_bf16<<<g, blk, 0, stream>>>(v_in, vb, n4);
  }
  // 2) W^T (bf16) so projections use the BT GEMM
  {
    dim3 g(DK_ / 32, D_ / 32);
    transpose_f32_bf16<<<g, blk, 0, stream>>>(Wq, WqT, D_, DK_);
    transpose_f32_bf16<<<g, blk, 0, stream>>>(Wk, WkT, D_, DK_);
    transpose_f32_bf16<<<g, blk, 0, stream>>>(Wv, WvT, D_, DK_);
  }
  // 3) projections: [8192,1024] x [1024,1024]^T -> bf16
  {
    dim3 g(DK_ / 128, (B_ * S_) / 128, 1);
    gemm_bt<unsigned short><<<g, blk, 0, stream>>>(qb, WqT, Qb, bq, B_ * S_, DK_, D_, 0, 0, 0, 1.f);
    gemm_bt<unsigned short><<<g, blk, 0, stream>>>(kb, WkT, Kb, bk, B_ * S_, DK_, D_, 0, 0, 0, 1.f);
    gemm_bt<unsigned short><<<g, blk, 0, stream>>>(vb, WvT, Vb, bv, B_ * S_, DV_, D_, 0, 0, 0, 1.f);
  }
  // 4) V -> V^T per batch (PV becomes a BT GEMM)
  {
    dim3 g(DV_ / 32, S_ / 32, B_);
    transpose_bf16_batched<<<g, blk, 0, stream>>>(Vb, Vt, S_, DV_);
  }
  // 5) scores = Q K^T / 32 (fp32), batched
  {
    dim3 g(S_ / 128, S_ / 128, B_);
    gemm_bt<float><<<g, blk, 0, stream>>>(Qb, Kb, scores, nullptr, S_, S_, DK_,
                                          (long)S_ * DK_, (long)S_ * DK_, (long)S_ * S_, 0.03125f);
  }
  // 6) softmax rows -> bf16 attn
  {
    dim3 g(B_ * S_);
    softmax_rows<<<g, blk, 0, stream>>>(scores, attn);
  }
  // 7) out = attn @ V  ==  attn[2048,2048] x Vt[1024,2048]^T, fp32 out
  {
    dim3 g(DV_ / 128, S_ / 128, B_);
    gemm_bt<float><<<g, blk, 0, stream>>>(attn, Vt, out, nullptr, S_, DV_, S_,
                                          (long)S_ * S_, (long)DV_ * S_, (long)S_ * DV_, 1.f);
  }
}

// Round 3
// 383.177 us; speedup vs baseline: 1.1004x; 1.1004x over previous
//
#include <hip/hip_runtime.h>
#include <stdint.h>

// Problem constants (B,S,D fixed by the reference)
#define B_  4
#define S_  2048
#define D_  1024
#define DK_ 1024
#define DV_ 1024

typedef __attribute__((ext_vector_type(8)))  short short8;    // 8 bf16 = 4 VGPRs (MFMA A/B frag)
typedef __attribute__((ext_vector_type(16))) float floatx16;  // 32x32 MFMA C/D frag

// async global->LDS DMA, 16B per lane, wave-uniform LDS base (lane scatters +lane*16B)
#define ASYNC16(gsrc, ldst)                                                        \
  __builtin_amdgcn_global_load_lds(                                                \
      (const __attribute__((address_space(1))) unsigned int*)(gsrc),               \
      (__attribute__((address_space(3))) unsigned int*)(ldst), 16, 0, 0)

// round-to-nearest-even fp32 -> bf16
__device__ __forceinline__ unsigned short f2bf(float f) {
  union { float f; uint32_t u; } v; v.f = f;
  uint32_t r = v.u + 0x7fffu + ((v.u >> 16) & 1u);
  return (unsigned short)(r >> 16);
}

// ---------------- fp32 -> bf16 elementwise ----------------
__global__ __launch_bounds__(256) void cvt_f32_bf16(const float* __restrict__ in,
                                                    unsigned short* __restrict__ out, int n4) {
  int i = blockIdx.x * blockDim.x + threadIdx.x;
  if (i >= n4) return;
  float4 v = ((const float4*)in)[i];
  ushort4 o;
  o.x = f2bf(v.x); o.y = f2bf(v.y); o.z = f2bf(v.z); o.w = f2bf(v.w);
  ((ushort4*)out)[i] = o;
}

// ---------------- transpose fp32 [rows,cols] -> bf16 [cols,rows] ----------------
__global__ __launch_bounds__(256) void transpose_f32_bf16(const float* __restrict__ in,
                                                          unsigned short* __restrict__ out,
                                                          int rows, int cols) {
  __shared__ float tile[32][33];
  int bx = blockIdx.x * 32, by = blockIdx.y * 32;
  int tx = threadIdx.x & 31, ty = threadIdx.x >> 5;
  for (int r = ty; r < 32; r += 8)
    tile[r][tx] = in[(long)(by + r) * cols + bx + tx];
  __syncthreads();
  for (int r = ty; r < 32; r += 8)
    out[(long)(bx + r) * rows + by + tx] = f2bf(tile[tx][r]);
}

// ---------------- transpose bf16 [rows,cols] -> bf16 [cols,rows], batched on z ----------------
__global__ __launch_bounds__(256) void transpose_bf16_batched(const unsigned short* __restrict__ in,
                                                              unsigned short* __restrict__ out,
                                                              int rows, int cols) {
  in  += (long)blockIdx.z * rows * cols;
  out += (long)blockIdx.z * rows * cols;
  __shared__ unsigned short tile[32][33];
  int bx = blockIdx.x * 32, by = blockIdx.y * 32;
  int tx = threadIdx.x & 31, ty = threadIdx.x >> 5;
  for (int r = ty; r < 32; r += 8)
    tile[r][tx] = in[(long)(by + r) * cols + bx + tx];
  __syncthreads();
  for (int r = ty; r < 32; r += 8)
    out[(long)(bx + r) * rows + by + tx] = tile[tx][r];
}

__device__ __forceinline__ void storeC(float* p, float v)          { *p = v; }
__device__ __forceinline__ void storeC(unsigned short* p, float v) { *p = f2bf(v); }

// ---------------- bf16 BT GEMM, 32x32x16 MFMA, BK=64 (two BK=32 half-tiles) ----------------
// C[M,N] = scale * (A[M,K] . B[N,K]^T) + bias.  128x128 block tile, 4 waves (2x2 of 64x64).
// LDS: As[h][128][32] for k-halves h=0,1 (ditto Bs). DMA chunks: 1KB = 16 rows x 32 cols,
// lane l -> row 16c+(l>>2), col-block (l&3). XOR swizzle applied on the GLOBAL source side:
// LDS[row][blk] holds global k-block (blk ^ (row&3)) -> frag ds_read_b128 is 2 lanes/bank (free),
// DMA stays wave-uniform-base contiguous (m104/m108 constraint).
// A/B frag (32x32x16): m(or n)=lane&31, k=(lane>>5)*8+j.  C/D (m74/m101 verified):
// col=lane&31, row=(reg&3)+8*(reg>>2)+4*(lane>>5).
// NOUT=3: fused QKV — blockIdx.x selects (A,C,bias) triple, B rows span 3072 (WqT||WkT||WvT).
template <typename OutT, int NOUT>
__global__ __launch_bounds__(256)
void gemm_bt32(const unsigned short* __restrict__ A0, const unsigned short* __restrict__ A1,
               const unsigned short* __restrict__ A2, const unsigned short* __restrict__ Bm,
               OutT* __restrict__ C0, OutT* __restrict__ C1, OutT* __restrict__ C2,
               const float* __restrict__ b0, const float* __restrict__ b1,
               const float* __restrict__ b2,
               int N, int K, long sA, long sB, long sC, float scale) {
  __shared__ __align__(16) unsigned short As[2][128 * 32];
  __shared__ __align__(16) unsigned short Bs[2][128 * 32];
  const int tid  = threadIdx.x;
  const int lane = tid & 63, wave = tid >> 6;
  const int wm = (wave >> 1) * 64, wn = (wave & 1) * 64;
  const int lm = lane & 31;           // row/col within 32-wide MFMA tile
  const int hi = lane >> 5;           // k-subgroup within a k16 step
  const long zb = blockIdx.z;
  const int m0  = blockIdx.y * 128;
  const int n0g = blockIdx.x * 128;

  // output/bias/A select (wave-uniform)
  const unsigned short* A = A0;
  OutT* C = C0;
  const float* bias = b0;
  int n0 = n0g;
  if (NOUT == 3) {
    int sel = n0g >> 10;
    n0 = n0g & 1023;
    if (sel == 1)      { A = A1; C = C1; bias = b1; }
    else if (sel == 2) { A = A2; C = C2; bias = b2; }
  }
  A += zb * sA;
  const unsigned short* Bp = Bm + zb * sB;
  C += zb * sC;

  // ---- staging setup: per wave 4 A-chunks + 4 B-chunks per K=64 iter ----
  const int rr   = lane >> 2;                  // 0..15 row within chunk
  const int ccol = (((lane & 3) ^ (rr & 3)) << 3);  // swizzled global col-block
  const unsigned short* agA = A  + (long)(m0  + 16 * wave + rr) * K + ccol;   // chunk c=wave, h=0
  const unsigned short* agB = Bp + (long)(n0g + 16 * wave + rr) * K + ccol;
  const unsigned short* ag0 = agA;                 // h=0, rows 16w..
  const unsigned short* ag1 = agA + 32;            // h=1, rows 16w..
  const unsigned short* ag2 = agA + 64 * (long)K;  // h=0, rows 64+16w..
  const unsigned short* ag3 = agA + 64 * (long)K + 32;
  const unsigned short* bg0 = agB;
  const unsigned short* bg1 = agB + 32;
  const unsigned short* bg2 = agB + 64 * (long)K;
  const unsigned short* bg3 = agB + 64 * (long)K + 32;
  unsigned short* al0 = &As[0][wave * 512];
  unsigned short* al1 = &As[1][wave * 512];
  unsigned short* al2 = &As[0][(wave + 4) * 512];
  unsigned short* al3 = &As[1][(wave + 4) * 512];
  unsigned short* bl0 = &Bs[0][wave * 512];
  unsigned short* bl1 = &Bs[1][wave * 512];
  unsigned short* bl2 = &Bs[0][(wave + 4) * 512];
  unsigned short* bl3 = &Bs[1][(wave + 4) * 512];

  floatx16 acc[2][2] = {};

  for (int kt = 0; kt < K; kt += 64) {
    __syncthreads();                    // previous compute done reading LDS
    ASYNC16(ag0, al0); ASYNC16(ag1, al1); ASYNC16(ag2, al2); ASYNC16(ag3, al3);
    ASYNC16(bg0, bl0); ASYNC16(bg1, bl1); ASYNC16(bg2, bl2); ASYNC16(bg3, bl3);
    __syncthreads();                    // drains vmcnt -> tiles visible

#pragma unroll
    for (int s = 0; s < 4; s++) {       // 4 k16 steps; h = s>>1 half, hs = s&1
      const int h = s >> 1, hs = s & 1;
      const int blk = (((hs << 1) | hi) ^ (lm & 3)) << 3;  // swizzled LDS col offset
      short8 af[2], bf[2];
#pragma unroll
      for (int i = 0; i < 2; i++)
        af[i] = *(const short8*)&As[h][(wm + i * 32 + lm) * 32 + blk];
#pragma unroll
      for (int j = 0; j < 2; j++)
        bf[j] = *(const short8*)&Bs[h][(wn + j * 32 + lm) * 32 + blk];
#pragma unroll
      for (int i = 0; i < 2; i++)
#pragma unroll
        for (int j = 0; j < 2; j++)
          acc[i][j] = __builtin_amdgcn_mfma_f32_32x32x16_bf16(af[i], bf[j], acc[i][j], 0, 0, 0);
    }
    ag0 += 64; ag1 += 64; ag2 += 64; ag3 += 64;
    bg0 += 64; bg1 += 64; bg2 += 64; bg3 += 64;
  }

  // ---- epilogue: C/D col=lane&31, row=(r&3)+8*(r>>2)+4*hi ----
#pragma unroll
  for (int i = 0; i < 2; i++) {
#pragma unroll
    for (int j = 0; j < 2; j++) {
      const int col = n0 + wn + j * 32 + lm;
      const float bv = bias ? bias[col] : 0.f;
#pragma unroll
      for (int r = 0; r < 16; r++) {
        const int row = m0 + wm + i * 32 + (r & 3) + ((r >> 2) << 3) + (hi << 2);
        storeC(C + (long)row * N + col, acc[i][j][r] * scale + bv);
      }
    }
  }
}

// ---------------- row softmax: fp32 [rows,2048] -> bf16 probs ----------------
__global__ __launch_bounds__(256) void softmax_rows(const float* __restrict__ Sc,
                                                    unsigned short* __restrict__ P) {
  const long row = blockIdx.x;
  const float* x = Sc + row * 2048;
  unsigned short* p = P + row * 2048;
  const int tid = threadIdx.x;
  float v[8];
  float m = -3.4e38f;
#pragma unroll
  for (int j = 0; j < 8; j++) { v[j] = x[tid + j * 256]; m = fmaxf(m, v[j]); }
#pragma unroll
  for (int off = 32; off > 0; off >>= 1) m = fmaxf(m, __shfl_xor(m, off, 64));
  __shared__ float redm[4], reds[4];
  if ((tid & 63) == 0) redm[tid >> 6] = m;
  __syncthreads();
  m = fmaxf(fmaxf(redm[0], redm[1]), fmaxf(redm[2], redm[3]));
  float s = 0.f;
#pragma unroll
  for (int j = 0; j < 8; j++) { v[j] = __expf(v[j] - m); s += v[j]; }
#pragma unroll
  for (int off = 32; off > 0; off >>= 1) s += __shfl_xor(s, off, 64);
  if ((tid & 63) == 0) reds[tid >> 6] = s;
  __syncthreads();
  s = reds[0] + reds[1] + reds[2] + reds[3];
  float inv = 1.f / s;
#pragma unroll
  for (int j = 0; j < 8; j++) p[tid + j * 256] = f2bf(v[j] * inv);
}

extern "C" void kernel_launch(void* const* d_in, const int* in_sizes, int n_in,
                              void* d_out, int out_size, void* d_ws, size_t ws_size,
                              hipStream_t stream) {
  const float* q_in = (const float*)d_in[0];
  const float* k_in = (const float*)d_in[1];
  const float* v_in = (const float*)d_in[2];
  const float* Wq   = (const float*)d_in[3];
  const float* bq   = (const float*)d_in[4];
  const float* Wk   = (const float*)d_in[5];
  const float* bk   = (const float*)d_in[6];
  const float* Wv   = (const float*)d_in[7];
  const float* bv   = (const float*)d_in[8];
  float* out = (float*)d_out;

  // ---- workspace layout (same as rounds 1-2; scores overlays dead regions) ----
  char* ws = (char*)d_ws;
  const long nX = (long)B_ * S_ * D_;   // 8388608 elems
  const long nW = (long)D_ * DK_;       // 1048576
  unsigned short* qb  = (unsigned short*)(ws);
  unsigned short* kb  = qb + nX;
  unsigned short* vb  = kb + nX;
  unsigned short* WqT = vb + nX;        // WqT||WkT||WvT contiguous = B[3072,1024]
  unsigned short* WkT = WqT + nW;
  unsigned short* WvT = WkT + nW;
  unsigned short* Vb  = WvT + nW;       // dead after V-transpose
  unsigned short* Qb  = Vb + nX;
  unsigned short* Kb  = Qb + nX;
  unsigned short* Vt  = Kb + nX;        // [B, DV, S]
  float*          scores = (float*)ws;  // overlay [0,64MB): qb/kb/vb/W/Vb dead by then
  unsigned short* attn   = Vt + nX;

  dim3 blk(256);

  // 1) inputs -> bf16
  {
    int n4 = (int)(nX / 4);
    dim3 g(n4 / 256);
    cvt_f32_bf16<<<g, blk, 0, stream>>>(q_in, qb, n4);
    cvt_f32_bf16<<<g, blk, 0, stream>>>(k_in, kb, n4);
    cvt_f32_bf16<<<g, blk, 0, stream>>>(v_in, vb, n4);
  }
  // 2) W^T (bf16)
  {
    dim3 g(DK_ / 32, D_ / 32);
    transpose_f32_bf16<<<g, blk, 0, stream>>>(Wq, WqT, D_, DK_);
    transpose_f32_bf16<<<g, blk, 0, stream>>>(Wk, WkT, D_, DK_);
    transpose_f32_bf16<<<g, blk, 0, stream>>>(Wv, WvT, D_, DK_);
  }
  // 3) fused QKV projection: x-tiles [0,8)->Q, [8,16)->K, [16,24)->V
  {
    dim3 g(3 * DK_ / 128, (B_ * S_) / 128, 1);
    gemm_bt32<unsigned short, 3><<<g, blk, 0, stream>>>(
        qb, kb, vb, WqT, Qb, Kb, Vb, bq, bk, bv, DK_, D_, 0, 0, 0, 1.f);
  }
  // 4) V -> V^T per batch
  {
    dim3 g(DV_ / 32, S_ / 32, B_);
    transpose_bf16_batched<<<g, blk, 0, stream>>>(Vb, Vt, S_, DV_);
  }
  // 5) scores = Q K^T / 32 (fp32), batched
  {
    dim3 g(S_ / 128, S_ / 128, B_);
    gemm_bt32<float, 1><<<g, blk, 0, stream>>>(
        Qb, nullptr, nullptr, Kb, scores, nullptr, nullptr, nullptr, nullptr, nullptr,
        S_, DK_, (long)S_ * DK_, (long)S_ * DK_, (long)S_ * S_, 0.03125f);
  }
  // 6) softmax rows -> bf16 attn
  {
    dim3 g(B_ * S_);
    softmax_rows<<<g, blk, 0, stream>>>(scores, attn);
  }
  // 7) out = attn @ V = attn[2048,2048] x Vt[1024,2048]^T, fp32 out
  {
    dim3 g(DV_ / 128, S_ / 128, B_);
    gemm_bt32<float, 1><<<g, blk, 0, stream>>>(
        attn, nullptr, nullptr, Vt, out, nullptr, nullptr, nullptr, nullptr, nullptr,
        DV_, S_, (long)S_ * S_, (long)DV_ * S_, (long)S_ * DV_, 1.f);
  }
}

// Round 4
// 362.956 us; speedup vs baseline: 1.1617x; 1.0557x over previous
//
#include <hip/hip_runtime.h>
#include <stdint.h>

// Problem constants (B,S,D fixed by the reference)
#define B_  4
#define S_  2048
#define D_  1024
#define DK_ 1024
#define DV_ 1024

typedef __attribute__((ext_vector_type(8)))  short short8;    // 8 bf16 = 4 VGPRs (MFMA A/B frag)
typedef __attribute__((ext_vector_type(16))) float floatx16;  // 32x32 MFMA C/D frag

// async global->LDS DMA, 16B per lane, wave-uniform LDS base (lane scatters +lane*16B)
#define ASYNC16(gsrc, ldst)                                                        \
  __builtin_amdgcn_global_load_lds(                                                \
      (const __attribute__((address_space(1))) unsigned int*)(gsrc),               \
      (__attribute__((address_space(3))) unsigned int*)(ldst), 16, 0, 0)

// round-to-nearest-even fp32 -> bf16
__device__ __forceinline__ unsigned short f2bf(float f) {
  union { float f; uint32_t u; } v; v.f = f;
  uint32_t r = v.u + 0x7fffu + ((v.u >> 16) & 1u);
  return (unsigned short)(r >> 16);
}
__device__ __forceinline__ float bf2f(unsigned short h) {
  union { float f; uint32_t u; } v; v.u = ((uint32_t)h) << 16;
  return v.f;
}

// ---------------- fp32 -> bf16, 3 tensors in one dispatch (z selects) ----------------
__global__ __launch_bounds__(256) void cvt3_f32_bf16(const float* __restrict__ a,
                                                     const float* __restrict__ b,
                                                     const float* __restrict__ c,
                                                     unsigned short* __restrict__ out, int n4) {
  const float* in = (blockIdx.z == 0) ? a : (blockIdx.z == 1) ? b : c;
  unsigned short* o = out + (long)blockIdx.z * n4 * 4;
  int i = blockIdx.x * 256 + threadIdx.x;
  if (i >= n4) return;
  float4 v = ((const float4*)in)[i];
  ushort4 u;
  u.x = f2bf(v.x); u.y = f2bf(v.y); u.z = f2bf(v.z); u.w = f2bf(v.w);
  ((ushort4*)o)[i] = u;
}

// ---------------- transpose fp32 [rows,cols] -> bf16 [cols,rows], 3 weights (z) ----------------
__global__ __launch_bounds__(256) void transpose3_f32_bf16(const float* __restrict__ W0,
                                                           const float* __restrict__ W1,
                                                           const float* __restrict__ W2,
                                                           unsigned short* __restrict__ out,
                                                           int rows, int cols) {
  const float* in = (blockIdx.z == 0) ? W0 : (blockIdx.z == 1) ? W1 : W2;
  unsigned short* o = out + (long)blockIdx.z * rows * cols;
  __shared__ float tile[32][33];
  int bx = blockIdx.x * 32, by = blockIdx.y * 32;
  int tx = threadIdx.x & 31, ty = threadIdx.x >> 5;
  for (int r = ty; r < 32; r += 8)
    tile[r][tx] = in[(long)(by + r) * cols + bx + tx];
  __syncthreads();
  for (int r = ty; r < 32; r += 8)
    o[(long)(bx + r) * rows + by + tx] = f2bf(tile[tx][r]);
}

// ---------------- transpose bf16 [rows,cols] -> bf16 [cols,rows], batched on z ----------------
__global__ __launch_bounds__(256) void transpose_bf16_batched(const unsigned short* __restrict__ in,
                                                              unsigned short* __restrict__ out,
                                                              int rows, int cols) {
  in  += (long)blockIdx.z * rows * cols;
  out += (long)blockIdx.z * rows * cols;
  __shared__ unsigned short tile[32][33];
  int bx = blockIdx.x * 32, by = blockIdx.y * 32;
  int tx = threadIdx.x & 31, ty = threadIdx.x >> 5;
  for (int r = ty; r < 32; r += 8)
    tile[r][tx] = in[(long)(by + r) * cols + bx + tx];
  __syncthreads();
  for (int r = ty; r < 32; r += 8)
    out[(long)(bx + r) * rows + by + tx] = tile[tx][r];
}

__device__ __forceinline__ void storeC(float* p, float v)          { *p = v; }
__device__ __forceinline__ void storeC(unsigned short* p, float v) { *p = f2bf(v); }

// ---------------- bf16 BT GEMM, 32x32x16 MFMA, BK=64 (two BK=32 half-tiles) ----------------
// C[M,N] = scale * (A[M,K] . B[N,K]^T) + bias.  128x128 block tile, 4 waves (2x2 of 64x64).
// NO swizzle (round-3's XOR swizzle quadrupled LDS bank conflicts — reverted).
// LDS: As[h][128][32] for k-halves h=0,1 (ditto Bs). DMA chunk: 1KB = 16 rows x 32 cols,
// lane l -> row 16c+(l>>2), col (l&3)*8 -- natural contiguous layout.
// A/B frag (32x32x16): m(or n)=lane&31, k-chunk=(s&1)*16+(lane>>5)*8.
// C/D (m74/m101 verified): col=lane&31, row=(reg&3)+8*(reg>>2)+4*(lane>>5).
// NOUT=3: fused QKV — blockIdx.x selects (A,C,bias) triple, B rows span 3072 (WqT||WkT||WvT).
template <typename OutT, int NOUT>
__global__ __launch_bounds__(256)
void gemm_bt32(const unsigned short* __restrict__ A0, const unsigned short* __restrict__ A1,
               const unsigned short* __restrict__ A2, const unsigned short* __restrict__ Bm,
               OutT* __restrict__ C0, OutT* __restrict__ C1, OutT* __restrict__ C2,
               const float* __restrict__ b0, const float* __restrict__ b1,
               const float* __restrict__ b2,
               int N, int K, long sA, long sB, long sC, float scale) {
  __shared__ __align__(16) unsigned short As[2][128 * 32];
  __shared__ __align__(16) unsigned short Bs[2][128 * 32];
  const int tid  = threadIdx.x;
  const int lane = tid & 63, wave = tid >> 6;
  const int wm = (wave >> 1) * 64, wn = (wave & 1) * 64;
  const int lm = lane & 31;           // row/col within 32-wide MFMA tile
  const int hi = lane >> 5;           // k-subgroup within a k16 step
  const long zb = blockIdx.z;
  const int m0  = blockIdx.y * 128;
  const int n0g = blockIdx.x * 128;

  // output/bias/A select (wave-uniform)
  const unsigned short* A = A0;
  OutT* C = C0;
  const float* bias = b0;
  int n0 = n0g;
  if (NOUT == 3) {
    int sel = n0g >> 10;
    n0 = n0g & 1023;
    if (sel == 1)      { A = A1; C = C1; bias = b1; }
    else if (sel == 2) { A = A2; C = C2; bias = b2; }
  }
  A += zb * sA;
  const unsigned short* Bp = Bm + zb * sB;
  C += zb * sC;

  // ---- staging: per wave 4 A-chunks + 4 B-chunks per K=64 iter (natural layout) ----
  const int rr = lane >> 2;                 // 0..15 row within chunk
  const int cc = (lane & 3) * 8;            // col chunk (elements)
  const unsigned short* agA = A  + (long)(m0  + 16 * wave + rr) * K + cc;
  const unsigned short* agB = Bp + (long)(n0g + 16 * wave + rr) * K + cc;
  const unsigned short* ag0 = agA;                 // h=0, rows 16w..
  const unsigned short* ag1 = agA + 32;            // h=1, rows 16w..
  const unsigned short* ag2 = agA + 64 * (long)K;  // h=0, rows 64+16w..
  const unsigned short* ag3 = agA + 64 * (long)K + 32;
  const unsigned short* bg0 = agB;
  const unsigned short* bg1 = agB + 32;
  const unsigned short* bg2 = agB + 64 * (long)K;
  const unsigned short* bg3 = agB + 64 * (long)K + 32;
  unsigned short* al0 = &As[0][wave * 512];
  unsigned short* al1 = &As[1][wave * 512];
  unsigned short* al2 = &As[0][(wave + 4) * 512];
  unsigned short* al3 = &As[1][(wave + 4) * 512];
  unsigned short* bl0 = &Bs[0][wave * 512];
  unsigned short* bl1 = &Bs[1][wave * 512];
  unsigned short* bl2 = &Bs[0][(wave + 4) * 512];
  unsigned short* bl3 = &Bs[1][(wave + 4) * 512];

  floatx16 acc[2][2] = {};

  for (int kt = 0; kt < K; kt += 64) {
    __syncthreads();                    // previous compute done reading LDS
    ASYNC16(ag0, al0); ASYNC16(ag1, al1); ASYNC16(ag2, al2); ASYNC16(ag3, al3);
    ASYNC16(bg0, bl0); ASYNC16(bg1, bl1); ASYNC16(bg2, bl2); ASYNC16(bg3, bl3);
    __syncthreads();                    // drains vmcnt -> tiles visible

#pragma unroll
    for (int s = 0; s < 4; s++) {       // 4 k16 steps; h = s>>1 half
      const int h   = s >> 1;
      const int off = (s & 1) * 16 + hi * 8;   // element offset within 32-col tile
      short8 af[2], bf[2];
#pragma unroll
      for (int i = 0; i < 2; i++)
        af[i] = *(const short8*)&As[h][(wm + i * 32 + lm) * 32 + off];
#pragma unroll
      for (int j = 0; j < 2; j++)
        bf[j] = *(const short8*)&Bs[h][(wn + j * 32 + lm) * 32 + off];
#pragma unroll
      for (int i = 0; i < 2; i++)
#pragma unroll
        for (int j = 0; j < 2; j++)
          acc[i][j] = __builtin_amdgcn_mfma_f32_32x32x16_bf16(af[i], bf[j], acc[i][j], 0, 0, 0);
    }
    ag0 += 64; ag1 += 64; ag2 += 64; ag3 += 64;
    bg0 += 64; bg1 += 64; bg2 += 64; bg3 += 64;
  }

  // ---- epilogue: C/D col=lane&31, row=(r&3)+8*(r>>2)+4*hi ----
#pragma unroll
  for (int i = 0; i < 2; i++) {
#pragma unroll
    for (int j = 0; j < 2; j++) {
      const int col = n0 + wn + j * 32 + lm;
      const float bv = bias ? bias[col] : 0.f;
#pragma unroll
      for (int r = 0; r < 16; r++) {
        const int row = m0 + wm + i * 32 + (r & 3) + ((r >> 2) << 3) + (hi << 2);
        storeC(C + (long)row * N + col, acc[i][j][r] * scale + bv);
      }
    }
  }
}

// ---------------- row softmax: bf16 [rows,2048] -> bf16 probs, vectorized ----------------
__global__ __launch_bounds__(256) void softmax_rows_bf16(const unsigned short* __restrict__ Sc,
                                                         unsigned short* __restrict__ P) {
  const long row = blockIdx.x;
  const int tid = threadIdx.x;
  short8 xv = ((const short8*)(Sc + row * 2048))[tid];
  float v[8];
  float m = -3.4e38f;
#pragma unroll
  for (int j = 0; j < 8; j++) { v[j] = bf2f((unsigned short)xv[j]); m = fmaxf(m, v[j]); }
#pragma unroll
  for (int off = 32; off > 0; off >>= 1) m = fmaxf(m, __shfl_xor(m, off, 64));
  __shared__ float redm[4], reds[4];
  if ((tid & 63) == 0) redm[tid >> 6] = m;
  __syncthreads();
  m = fmaxf(fmaxf(redm[0], redm[1]), fmaxf(redm[2], redm[3]));
  float s = 0.f;
#pragma unroll
  for (int j = 0; j < 8; j++) { v[j] = __expf(v[j] - m); s += v[j]; }
#pragma unroll
  for (int off = 32; off > 0; off >>= 1) s += __shfl_xor(s, off, 64);
  if ((tid & 63) == 0) reds[tid >> 6] = s;
  __syncthreads();
  s = reds[0] + reds[1] + reds[2] + reds[3];
  float inv = 1.f / s;
  short8 ov;
#pragma unroll
  for (int j = 0; j < 8; j++) ov[j] = (short)f2bf(v[j] * inv);
  ((short8*)(P + row * 2048))[tid] = ov;
}

extern "C" void kernel_launch(void* const* d_in, const int* in_sizes, int n_in,
                              void* d_out, int out_size, void* d_ws, size_t ws_size,
                              hipStream_t stream) {
  const float* q_in = (const float*)d_in[0];
  const float* k_in = (const float*)d_in[1];
  const float* v_in = (const float*)d_in[2];
  const float* Wq   = (const float*)d_in[3];
  const float* bq   = (const float*)d_in[4];
  const float* Wk   = (const float*)d_in[5];
  const float* bk   = (const float*)d_in[6];
  const float* Wv   = (const float*)d_in[7];
  const float* bv   = (const float*)d_in[8];
  float* out = (float*)d_out;

  // ---- workspace layout; scores (bf16, 33.5MB) overlays dead qb/kb regions ----
  char* ws = (char*)d_ws;
  const long nX = (long)B_ * S_ * D_;   // 8388608 elems
  const long nW = (long)D_ * DK_;       // 1048576
  unsigned short* qb  = (unsigned short*)(ws);
  unsigned short* kb  = qb + nX;
  unsigned short* vb  = kb + nX;
  unsigned short* WqT = vb + nX;        // WqT||WkT||WvT contiguous = B[3072,1024]
  unsigned short* Vb  = WqT + 3 * nW;   // dead after V-transpose
  unsigned short* Qb  = Vb + nX;
  unsigned short* Kb  = Qb + nX;
  unsigned short* Vt  = Kb + nX;        // [B, DV, S]
  unsigned short* scoresB = (unsigned short*)ws;  // bf16 [B,S,S] overlay: qb/kb/vb dead by then
  unsigned short* attn    = Vt + nX;

  dim3 blk(256);

  // 1) inputs -> bf16 (one dispatch, z selects tensor; qb/kb/vb contiguous)
  {
    int n4 = (int)(nX / 4);
    dim3 g(n4 / 256, 1, 3);
    cvt3_f32_bf16<<<g, blk, 0, stream>>>(q_in, k_in, v_in, qb, n4);
  }
  // 2) W^T (bf16), one dispatch
  {
    dim3 g(DK_ / 32, D_ / 32, 3);
    transpose3_f32_bf16<<<g, blk, 0, stream>>>(Wq, Wk, Wv, WqT, D_, DK_);
  }
  // 3) fused QKV projection: x-tiles [0,8)->Q, [8,16)->K, [16,24)->V
  {
    dim3 g(3 * DK_ / 128, (B_ * S_) / 128, 1);
    gemm_bt32<unsigned short, 3><<<g, blk, 0, stream>>>(
        qb, kb, vb, WqT, Qb, Kb, Vb, bq, bk, bv, DK_, D_, 0, 0, 0, 1.f);
  }
  // 4) V -> V^T per batch
  {
    dim3 g(DV_ / 32, S_ / 32, B_);
    transpose_bf16_batched<<<g, blk, 0, stream>>>(Vb, Vt, S_, DV_);
  }
  // 5) scores = Q K^T / 32 -> bf16, batched
  {
    dim3 g(S_ / 128, S_ / 128, B_);
    gemm_bt32<unsigned short, 1><<<g, blk, 0, stream>>>(
        Qb, nullptr, nullptr, Kb, scoresB, nullptr, nullptr, nullptr, nullptr, nullptr,
        S_, DK_, (long)S_ * DK_, (long)S_ * DK_, (long)S_ * S_, 0.03125f);
  }
  // 6) softmax rows -> bf16 attn
  {
    dim3 g(B_ * S_);
    softmax_rows_bf16<<<g, blk, 0, stream>>>(scoresB, attn);
  }
  // 7) out = attn @ V = attn[2048,2048] x Vt[1024,2048]^T, fp32 out
  {
    dim3 g(DV_ / 128, S_ / 128, B_);
    gemm_bt32<float, 1><<<g, blk, 0, stream>>>(
        attn, nullptr, nullptr, Vt, out, nullptr, nullptr, nullptr, nullptr, nullptr,
        DV_, S_, (long)S_ * S_, (long)DV_ * S_, (long)S_ * DV_, 1.f);
  }
}